// Round 13
// baseline (100.455 us; speedup 1.0000x reference)
//
#include <hip/hip_runtime.h>

// Chamfer distance via bf16 MFMA with hi/lo split (fp32-grade precision).
// d(p,q) = ||p||^2 + ||q||^2 - 2 p.q.
// A row (target): [uh x3, uh x3, ul x3, ul x3, wh wm wl, 0], u=-2t, w=||t||^2
// B col (query):  [qh x3, ql x3, qh x3, ql x3, 1 1 1, 0]
// => D = -2 t.q + ||t||^2 + O(1e-5); query ||q||^2 added after the min.
//
// R13: break the MFMA->min latency chain (the invariant across R4-R12).
//  - min consumer SOFTWARE-PIPELINED one iteration behind the MFMA producer:
//    iteration i issues MFMAs(i) then min3s on d(i-1) (results long ready).
//    unroll 2 => register renaming removes the rotation copies.
//  - s_setprio(1) around the MFMA quad (independent blocks, attn-like).
//  - LB(256,2): peak live regs ~230 (8 f32x16 d's in flight). Spill history:
//    R8 full-unroll 3.4GB scratch, R9 rg[] 80MB — check WRITE_SIZE ~1MB.
//  - rest is R12-exact: z-split x2, SLICE=512 dbuf, async global_load_lds,
//    atomicMin minbuf + reduce.

typedef short bf16x8 __attribute__((ext_vector_type(8)));
typedef float f32x16 __attribute__((ext_vector_type(16)));

#define B_SZ   8
#define NPTS   8192
#define TOTAL  (B_SZ * NPTS)     // 65536
#define BLOCK  256
#define QB     256               // queries per nn block (4 waves x 64)
#define ZSPLIT 2
#define HALF   (NPTS / ZSPLIT)   // 4096 targets per z-half
#define SLICE  512               // targets per LDS stage
#define NSTAGE (HALF / SLICE)    // 8
#define TILES  (SLICE / 32)      // 16
#define BUFB   (SLICE * 32)      // 16384 bytes per LDS buffer
#define RED_GRID 64

// round-to-nearest bf16 (half-up via +0x8000 carry), return remainder
__device__ __forceinline__ unsigned short bf16rn(float f, float* rem) {
    unsigned u = __float_as_uint(f);
    unsigned h = (u + 0x8000u) & 0xFFFF0000u;
    *rem = f - __uint_as_float(h);
    return (unsigned short)(h >> 16);
}

// One thread per point; blockIdx.y: 0 = gt, 1 = pred.  (round-4/6 exact)
__global__ __launch_bounds__(BLOCK) void chamfer_prep_mfma(
    const float* __restrict__ gt, const float* __restrict__ pred,
    uint4* __restrict__ TgA, uint4* __restrict__ TgB, float* __restrict__ Wg,
    uint4* __restrict__ TpA, uint4* __restrict__ TpB, float* __restrict__ Wp)
{
    int i = blockIdx.x * BLOCK + threadIdx.x;
    const float* src = blockIdx.y ? pred : gt;
    uint4* TA = blockIdx.y ? TpA : TgA;
    uint4* TB = blockIdx.y ? TpB : TgB;
    float* W  = blockIdx.y ? Wp  : Wg;

    float x = src[3 * (size_t)i + 0];
    float y = src[3 * (size_t)i + 1];
    float z = src[3 * (size_t)i + 2];
    float w = fmaf(x, x, fmaf(y, y, z * z));
    W[i] = w;

    float ux = -2.f * x, uy = -2.f * y, uz = -2.f * z;
    float rx, ry, rz, dx, dy, dz, rw1, rw2, rw3;
    unsigned short uhx = bf16rn(ux, &rx), uhy = bf16rn(uy, &ry), uhz = bf16rn(uz, &rz);
    unsigned short ulx = bf16rn(rx, &dx), uly = bf16rn(ry, &dy), ulz = bf16rn(rz, &dz);
    unsigned short wh = bf16rn(w, &rw1), wm = bf16rn(rw1, &rw2), wl = bf16rn(rw2, &rw3);
    union { unsigned short s[16]; uint4 v[2]; } A;
    A.s[0] = uhx; A.s[1] = uhy; A.s[2]  = uhz;
    A.s[3] = uhx; A.s[4] = uhy; A.s[5]  = uhz;
    A.s[6] = ulx; A.s[7] = uly; A.s[8]  = ulz;
    A.s[9] = ulx; A.s[10] = uly; A.s[11] = ulz;
    A.s[12] = wh; A.s[13] = wm; A.s[14] = wl; A.s[15] = 0;
    TA[2 * (size_t)i]     = A.v[0];
    TA[2 * (size_t)i + 1] = A.v[1];

    float sx, sy, sz, ex, ey, ez;
    unsigned short qhx = bf16rn(x, &sx), qhy = bf16rn(y, &sy), qhz = bf16rn(z, &sz);
    unsigned short qlx = bf16rn(sx, &ex), qly = bf16rn(sy, &ey), qlz = bf16rn(sz, &ez);
    union { unsigned short s[16]; uint4 v[2]; } Bb;
    Bb.s[0] = qhx; Bb.s[1] = qhy; Bb.s[2]  = qhz;
    Bb.s[3] = qlx; Bb.s[4] = qly; Bb.s[5]  = qlz;
    Bb.s[6] = qhx; Bb.s[7] = qhy; Bb.s[8]  = qhz;
    Bb.s[9] = qlx; Bb.s[10] = qly; Bb.s[11] = qlz;
    Bb.s[12] = 0x3F80; Bb.s[13] = 0x3F80; Bb.s[14] = 0x3F80; Bb.s[15] = 0;
    TB[2 * (size_t)i]     = Bb.v[0];
    TB[2 * (size_t)i + 1] = Bb.v[1];
}

// async 16B global->LDS (direct-to-LDS DMA, no VGPR round-trip; R10-proven)
__device__ __forceinline__ void gload_lds16(const void* g, void* l) {
    __builtin_amdgcn_global_load_lds(
        (const __attribute__((address_space(1))) unsigned int*)g,
        (__attribute__((address_space(3))) unsigned int*)l, 16, 0, 0);
}

// macc = min(macc, a, b) elementwise: 16 v_min3_f32 when fused, depth 1
__device__ __forceinline__ f32x16 min3x16(f32x16 m, f32x16 a, f32x16 b) {
#pragma unroll
    for (int j = 0; j < 16; ++j) m[j] = fminf(fminf(m[j], a[j]), b[j]);
    return m;
}

// final 16 -> 1 tree (min3-fusable), once per kernel
__device__ __forceinline__ float mintree(f32x16 m) {
    float r0 = fminf(fminf(m[0], m[1]), m[2]);
    float r1 = fminf(fminf(m[3], m[4]), m[5]);
    float r2 = fminf(fminf(m[6], m[7]), m[8]);
    float r3 = fminf(fminf(m[9], m[10]), m[11]);
    float r4 = fminf(fminf(m[12], m[13]), m[14]);
    float s0 = fminf(fminf(r0, r1), r2);
    float s1 = fminf(fminf(r3, r4), m[15]);
    return fminf(s0, s1);
}

#define MFMA32(a, b, c) __builtin_amdgcn_mfma_f32_32x32x16_bf16((a), (b), (c), 0, 0, 0)

// grid (32 qb, 8 b, 4 = dir*2+zs), 256 threads / 4 waves, LB(256,2).
// Wave w: queries qb*256 + w*64 .. +63 (two 32-col B-sets); block covers
// targets [zs*HALF, (zs+1)*HALF) in 8 double-buffered stages.
__global__ __launch_bounds__(BLOCK, 2) void chamfer_nn_mfma(
    const uint4* __restrict__ TgA, const uint4* __restrict__ TpB,
    const float* __restrict__ Wp, unsigned* __restrict__ minP,
    const uint4* __restrict__ TpA, const uint4* __restrict__ TgB,
    const float* __restrict__ Wg, unsigned* __restrict__ minG)
{
    __shared__ uint4 tileU[2 * SLICE * 2];   // 2 x 16 KiB A-form buffers
    char* tileC = (char*)tileU;

    const int qb = blockIdx.x, b = blockIdx.y;
    const int dir = blockIdx.z >> 1, zs = blockIdx.z & 1;
    const int t = threadIdx.x, lane = t & 63, wid = t >> 6;
    const int col = lane & 31, hi = lane >> 5;

    const uint4* TA = dir ? TpA : TgA;
    const uint4* TB = dir ? TgB : TpB;
    const float* WQ = dir ? Wg  : Wp;
    unsigned*  minb = dir ? minG : minP;

    // B fragments (round-4/6 exact addressing)
    const int qblk = qb * QB + wid * 64;
    const char* TBc = (const char*)(TB + ((size_t)b * NPTS + qblk) * 2);
    bf16x8 bq0 = *(const bf16x8*)(TBc + (size_t)col * 32 + hi * 16);
    bf16x8 bq1 = *(const bf16x8*)(TBc + (size_t)(col + 32) * 32 + hi * 16);

    f32x16 zacc;
#pragma unroll
    for (int j = 0; j < 16; ++j) zacc[j] = 0.f;
    f32x16 macc0 = zacc + 3.0e38f;
    f32x16 macc1 = macc0;
    // swizzled A-frag READ base (HW-proven since R4); tile tt at +tt*1024
    const int abase = (col * 32 + hi * 16) ^ (((col >> 2) & 7) << 4);

    // staging (R10/R11/R12-proven): 1024 granules/stage; wave wid owns chunks
    // wid*4+it; LINEAR LDS dest + XOR-pre-swizzled global source lane.
    const uint4* TAb = TA + ((size_t)b * NPTS + (size_t)zs * HALF) * 2;
    const int swzlane = lane ^ (lane >> 3);
    const uint4* gsrc0 = TAb + wid * 256 + swzlane;
    char* ldst0 = tileC + wid * 4096;

    // prologue: stage 0 into buf0 (async; drained by barrier's vmcnt)
#pragma unroll
    for (int it = 0; it < 4; ++it)
        gload_lds16(gsrc0 + it * 64, ldst0 + it * 1024);
    __syncthreads();

    for (int st = 0; st < NSTAGE; ++st) {
        const int cur = (st & 1) * BUFB;
        if (st + 1 < NSTAGE) {               // issue next stage EARLY (async)
            const uint4* gs = gsrc0 + (size_t)(st + 1) * (SLICE * 2);
            char* ld = ldst0 + (cur ^ BUFB);
#pragma unroll
            for (int it = 0; it < 4; ++it)
                gload_lds16(gs + it * 64, ld + it * 1024);
        }

        // Software-pipelined tile-pair loop: MFMAs(i) issue, then min3s
        // consume d(i-1) — never waits on MFMA result latency.
        const char* tb = tileC + cur + abase;
        bf16x8 a0 = *(const bf16x8*)(tb);
        bf16x8 a1 = *(const bf16x8*)(tb + 1024);
        __builtin_amdgcn_s_setprio(1);
        f32x16 p0e = MFMA32(a0, bq0, zacc);
        f32x16 p1e = MFMA32(a0, bq1, zacc);
        f32x16 p0o = MFMA32(a1, bq0, zacc);
        f32x16 p1o = MFMA32(a1, bq1, zacc);
        __builtin_amdgcn_s_setprio(0);
#pragma unroll 2
        for (int tp = 1; tp < TILES / 2; ++tp) {
            bf16x8 b0 = *(const bf16x8*)(tb + (2 * tp) * 1024);
            bf16x8 b1 = *(const bf16x8*)(tb + (2 * tp + 1) * 1024);
            __builtin_amdgcn_s_setprio(1);
            f32x16 n0e = MFMA32(b0, bq0, zacc);
            f32x16 n1e = MFMA32(b0, bq1, zacc);
            f32x16 n0o = MFMA32(b1, bq0, zacc);
            f32x16 n1o = MFMA32(b1, bq1, zacc);
            __builtin_amdgcn_s_setprio(0);
            macc0 = min3x16(macc0, p0e, p0o);   // consume PREVIOUS pair
            macc1 = min3x16(macc1, p1e, p1o);
            p0e = n0e; p1e = n1e; p0o = n0o; p1o = n1o;  // renamed at unroll 2
        }
        macc0 = min3x16(macc0, p0e, p0o);       // drain the pipeline
        macc1 = min3x16(macc1, p1e, p1o);

        __syncthreads();                     // one barrier/stage (R8/R10 scheme)
    }

    // epilogue: 16->1 trees, combine row-halves, add ||q||^2, atomicMin
    float m0 = mintree(macc0);
    float m1 = mintree(macc1);
    m0 = fminf(m0, __shfl_xor(m0, 32));
    m1 = fminf(m1, __shfl_xor(m1, 32));
    // thread t <-> query qb*QB + t (R6-proven mapping)
    int qi = (int)((size_t)b * NPTS) + qb * QB + t;
    float wq = WQ[qi];
    float d = fmaxf((lane < 32 ? m0 : m1) + wq, 0.0f);
    atomicMin(&minb[qi], __float_as_uint(d));
}

// out += sum(a)*sc + sum(b)*sc  (multi-block; out zero-initialized)
__global__ __launch_bounds__(BLOCK) void chamfer_reduce(
    const float* __restrict__ a, const float* __restrict__ b,
    float* __restrict__ out, float sc)
{
    __shared__ float part[BLOCK / 64];
    float s = 0.f;
    int tid = blockIdx.x * BLOCK + threadIdx.x;
    int stride = gridDim.x * BLOCK;
    const float4* a4 = (const float4*)a;
    const float4* b4 = (const float4*)b;
    for (int i = tid; i < TOTAL / 4; i += stride) {
        float4 va = a4[i], vb = b4[i];
        s += (va.x + va.y + va.z + va.w) + (vb.x + vb.y + vb.z + vb.w);
    }
    s *= sc;
    for (int o = 32; o > 0; o >>= 1) s += __shfl_down(s, o, 64);
    int w = threadIdx.x >> 6;
    if ((threadIdx.x & 63) == 0) part[w] = s;
    __syncthreads();
    if (threadIdx.x == 0) {
        float tot = 0.f;
#pragma unroll
        for (int i = 0; i < BLOCK / 64; ++i) tot += part[i];
        atomicAdd(out, tot);
    }
}

extern "C" void kernel_launch(void* const* d_in, const int* in_sizes, int n_in,
                              void* d_out, int out_size, void* d_ws, size_t ws_size,
                              hipStream_t stream) {
    const float* pred = (const float*)d_in[0];   // [B, N, 3]
    const float* gt   = (const float*)d_in[1];   // [B, M, 3]
    float* out = (float*)d_out;

    // ws layout: TgA, TpA, TgB, TpB (32B/point), Wg, Wp, minP, minG
    char* ws = (char*)d_ws;
    uint4* TgA = (uint4*)(ws);
    uint4* TpA = (uint4*)(ws + (size_t)TOTAL * 32);
    uint4* TgB = (uint4*)(ws + (size_t)TOTAL * 64);
    uint4* TpB = (uint4*)(ws + (size_t)TOTAL * 96);
    float* Wg  = (float*)(ws + (size_t)TOTAL * 128);
    float* Wp  = (float*)(ws + (size_t)TOTAL * 132);
    unsigned* minP = (unsigned*)(ws + (size_t)TOTAL * 136);
    unsigned* minG = (unsigned*)(ws + (size_t)TOTAL * 140);

    hipMemsetAsync(minP, 0x7f, (size_t)TOTAL * 8, stream);  // minP+minG ~3.39e38
    hipMemsetAsync(out, 0, sizeof(float), stream);

    chamfer_prep_mfma<<<dim3(TOTAL / BLOCK, 2), BLOCK, 0, stream>>>(
        gt, pred, TgA, TgB, Wg, TpA, TpB, Wp);

    chamfer_nn_mfma<<<dim3(NPTS / QB, B_SZ, 2 * ZSPLIT), BLOCK, 0, stream>>>(
        TgA, TpB, Wp, minP, TpA, TgB, Wg, minG);

    chamfer_reduce<<<RED_GRID, BLOCK, 0, stream>>>(
        (const float*)minP, (const float*)minG, out, 1.0f / (float)TOTAL);
}

// Round 14
// 94.775 us; speedup vs baseline: 1.0599x; 1.0599x over previous
//
#include <hip/hip_runtime.h>

// Chamfer distance via bf16 MFMA with hi/lo split (fp32-grade precision).
// d(p,q) = ||p||^2 + ||q||^2 - 2 p.q.
// A row (target): [uh x3, uh x3, ul x3, ul x3, wh wm wl, 0], u=-2t, w=||t||^2
// B col (query):  [qh x3, ql x3, qh x3, ql x3, 1 1 1, 0]
// => D = -2 t.q + ||t||^2 + O(1e-5); query ||q||^2 added after the min.
//
// R14 consolidation:
//  - 3 graph nodes: memset(out) + prep(A-forms only) + fused nn.
//    B-fragments and ||q||^2 built IN-KERNEL from raw coords (no TB/W arrays,
//    no minbuf/atomicMin/reduce).
//  - nn inner loop: software-pipelined tile-pairs, min3 consumers interleaved
//    BETWEEN MFMA issues, NO setprio (R13's setprio = scheduling barrier).
//  - async global_load_lds dbuf staging (R10-proven), fused epilogue (R6-proven).
// Spill history: R8 full-unroll 3.4GB, R9 rg[] 80MB -> LB(256,2), unroll 2,
// zero-VGPR staging. Check WRITE_SIZE ~<1MB.

typedef short bf16x8 __attribute__((ext_vector_type(8)));
typedef float f32x16 __attribute__((ext_vector_type(16)));

#define B_SZ   8
#define NPTS   8192
#define TOTAL  (B_SZ * NPTS)     // 65536
#define BLOCK  256
#define QB     256               // queries per nn block (4 waves x 64)
#define SLICE  1024              // targets per LDS stage
#define NSTAGE (NPTS / SLICE)    // 8
#define TILES  (SLICE / 32)      // 32
#define BUFB   (SLICE * 32)      // 32768 bytes per LDS buffer

// round-to-nearest bf16 (half-up via +0x8000 carry), return remainder
__device__ __forceinline__ unsigned short bf16rn(float f, float* rem) {
    unsigned u = __float_as_uint(f);
    unsigned h = (u + 0x8000u) & 0xFFFF0000u;
    *rem = f - __uint_as_float(h);
    return (unsigned short)(h >> 16);
}

// One thread per point; blockIdx.y: 0 = gt, 1 = pred. A-forms only.
__global__ __launch_bounds__(BLOCK) void chamfer_prep_mfma(
    const float* __restrict__ gt, const float* __restrict__ pred,
    uint4* __restrict__ TgA, uint4* __restrict__ TpA)
{
    int i = blockIdx.x * BLOCK + threadIdx.x;
    const float* src = blockIdx.y ? pred : gt;
    uint4* TA = blockIdx.y ? TpA : TgA;

    float x = src[3 * (size_t)i + 0];
    float y = src[3 * (size_t)i + 1];
    float z = src[3 * (size_t)i + 2];
    float w = fmaf(x, x, fmaf(y, y, z * z));

    float ux = -2.f * x, uy = -2.f * y, uz = -2.f * z;
    float rx, ry, rz, jk, rw1, rw2;
    unsigned short uhx = bf16rn(ux, &rx), uhy = bf16rn(uy, &ry), uhz = bf16rn(uz, &rz);
    unsigned short ulx = bf16rn(rx, &jk), uly = bf16rn(ry, &jk), ulz = bf16rn(rz, &jk);
    unsigned short wh = bf16rn(w, &rw1), wm = bf16rn(rw1, &rw2), wl = bf16rn(rw2, &jk);
    union { unsigned short s[16]; uint4 v[2]; } A;
    A.s[0] = uhx; A.s[1] = uhy; A.s[2]  = uhz;
    A.s[3] = uhx; A.s[4] = uhy; A.s[5]  = uhz;
    A.s[6] = ulx; A.s[7] = uly; A.s[8]  = ulz;
    A.s[9] = ulx; A.s[10] = uly; A.s[11] = ulz;
    A.s[12] = wh; A.s[13] = wm; A.s[14] = wl; A.s[15] = 0;
    TA[2 * (size_t)i]     = A.v[0];
    TA[2 * (size_t)i + 1] = A.v[1];
}

// async 16B global->LDS (direct-to-LDS DMA; R10-proven)
__device__ __forceinline__ void gload_lds16(const void* g, void* l) {
    __builtin_amdgcn_global_load_lds(
        (const __attribute__((address_space(1))) unsigned int*)g,
        (__attribute__((address_space(3))) unsigned int*)l, 16, 0, 0);
}

// macc = min(macc, a, b) elementwise: 16 v_min3_f32 when fused, depth 1
__device__ __forceinline__ f32x16 min3x16(f32x16 m, f32x16 a, f32x16 b) {
#pragma unroll
    for (int j = 0; j < 16; ++j) m[j] = fminf(fminf(m[j], a[j]), b[j]);
    return m;
}

// final 16 -> 1 tree (min3-fusable), once per kernel
__device__ __forceinline__ float mintree(f32x16 m) {
    float r0 = fminf(fminf(m[0], m[1]), m[2]);
    float r1 = fminf(fminf(m[3], m[4]), m[5]);
    float r2 = fminf(fminf(m[6], m[7]), m[8]);
    float r3 = fminf(fminf(m[9], m[10]), m[11]);
    float r4 = fminf(fminf(m[12], m[13]), m[14]);
    float s0 = fminf(fminf(r0, r1), r2);
    float s1 = fminf(fminf(r3, r4), m[15]);
    return fminf(s0, s1);
}

// build this lane's 16B B-fragment half for query (x,y,z); hi selects half.
// B record: [qh x3, ql x3, qh x3, ql x3, 1 1 1, 0] (R4-proven layout).
__device__ __forceinline__ bf16x8 makeB(float x, float y, float z, int hi) {
    float rx, ry, rz, jk;
    unsigned short qhx = bf16rn(x, &rx), qhy = bf16rn(y, &ry), qhz = bf16rn(z, &rz);
    unsigned short qlx = bf16rn(rx, &jk), qly = bf16rn(ry, &jk), qlz = bf16rn(rz, &jk);
    bf16x8 r;
    if (hi == 0) {   // K slots 0..7
        r[0] = (short)qhx; r[1] = (short)qhy; r[2] = (short)qhz;
        r[3] = (short)qlx; r[4] = (short)qly; r[5] = (short)qlz;
        r[6] = (short)qhx; r[7] = (short)qhy;
    } else {         // K slots 8..15
        r[0] = (short)qhz; r[1] = (short)qlx; r[2] = (short)qly;
        r[3] = (short)qlz; r[4] = (short)0x3F80; r[5] = (short)0x3F80;
        r[6] = (short)0x3F80; r[7] = 0;
    }
    return r;
}

#define MFMA32(a, b, c) __builtin_amdgcn_mfma_f32_32x32x16_bf16((a), (b), (c), 0, 0, 0)

// grid (32 qb, 8 b, 2 dir), 256 threads / 4 waves, 2 blocks/CU.
// Wave w: queries qb*256 + w*64 .. +63 (two 32-col B-sets); all 8192 targets
// in 8 double-buffered LDS stages. One atomicAdd per block.
__global__ __launch_bounds__(BLOCK, 2) void chamfer_nn_fused(
    const uint4* __restrict__ TgA, const uint4* __restrict__ TpA,
    const float* __restrict__ pred, const float* __restrict__ gt,
    float* __restrict__ out)
{
    __shared__ uint4 tileU[2 * SLICE * 2];   // 2 x 32 KiB A-form buffers
    __shared__ float psum[4];
    char* tileC = (char*)tileU;

    const int qb = blockIdx.x, b = blockIdx.y, dir = blockIdx.z;
    const int t = threadIdx.x, lane = t & 63, wid = t >> 6;
    const int col = lane & 31, hi = lane >> 5;

    const uint4*  TA  = dir ? TpA : TgA;
    const float*  qry = dir ? gt  : pred;

    // B fragments + ||q||^2 built in-kernel (layout proven R4; mapping R6):
    // bq0 <- query qblk+col, bq1 <- query qblk+32+col.
    const int qblk = qb * QB + wid * 64;
    const float* qb0 = qry + 3 * ((size_t)b * NPTS + qblk + col);
    const float* qb1 = qb0 + 96;             // +32 queries
    float x0 = qb0[0], y0 = qb0[1], z0 = qb0[2];
    float x1 = qb1[0], y1 = qb1[1], z1 = qb1[2];
    bf16x8 bq0 = makeB(x0, y0, z0, hi);
    bf16x8 bq1 = makeB(x1, y1, z1, hi);
    // epilogue wq: thread t <-> query qb*QB+t; lane<32 -> q0, lane>=32 -> q1
    float wq = (lane < 32) ? fmaf(x0, x0, fmaf(y0, y0, z0 * z0))
                           : fmaf(x1, x1, fmaf(y1, y1, z1 * z1));

    f32x16 zacc;
#pragma unroll
    for (int j = 0; j < 16; ++j) zacc[j] = 0.f;
    f32x16 macc0 = zacc + 3.0e38f;
    f32x16 macc1 = macc0;
    // swizzled A-frag READ base (HW-proven since R4); tile tt at +tt*1024
    const int abase = (col * 32 + hi * 16) ^ (((col >> 2) & 7) << 4);

    // staging (R10-proven): 2048 granules/stage; wave wid owns 8 chunks;
    // LINEAR LDS dest + XOR-pre-swizzled global source lane.
    const uint4* TAb = TA + (size_t)b * NPTS * 2;
    const int swzlane = lane ^ (lane >> 3);
    const uint4* gsrc0 = TAb + wid * 512 + swzlane;
    char* ldst0 = tileC + wid * 8192;

    // prologue: stage 0 into buf0 (async; drained by barrier's vmcnt)
#pragma unroll
    for (int it = 0; it < 8; ++it)
        gload_lds16(gsrc0 + it * 64, ldst0 + it * 1024);
    __syncthreads();

    for (int st = 0; st < NSTAGE; ++st) {
        const int cur = (st & 1) * BUFB;
        if (st + 1 < NSTAGE) {               // issue next stage EARLY (async)
            const uint4* gs = gsrc0 + (size_t)(st + 1) * (SLICE * 2);
            char* ld = ldst0 + (cur ^ BUFB);
#pragma unroll
            for (int it = 0; it < 8; ++it)
                gload_lds16(gs + it * 64, ld + it * 1024);
        }

        // software-pipelined tile-pair loop, min3 consumers INTERLEAVED
        // between MFMA issues (no setprio -> scheduler free to overlap).
        const char* tb = tileC + cur + abase;
        bf16x8 a0 = *(const bf16x8*)(tb);
        bf16x8 a1 = *(const bf16x8*)(tb + 1024);
        f32x16 p0e = MFMA32(a0, bq0, zacc);
        f32x16 p1e = MFMA32(a0, bq1, zacc);
        f32x16 p0o = MFMA32(a1, bq0, zacc);
        f32x16 p1o = MFMA32(a1, bq1, zacc);
#pragma unroll 2
        for (int tp = 1; tp < TILES / 2; ++tp) {
            bf16x8 b0 = *(const bf16x8*)(tb + (2 * tp) * 1024);
            bf16x8 b1 = *(const bf16x8*)(tb + (2 * tp + 1) * 1024);
            f32x16 n0e = MFMA32(b0, bq0, zacc);
            macc0 = min3x16(macc0, p0e, p0o);     // prev results: ready
            f32x16 n1e = MFMA32(b0, bq1, zacc);
            macc1 = min3x16(macc1, p1e, p1o);
            f32x16 n0o = MFMA32(b1, bq0, zacc);
            f32x16 n1o = MFMA32(b1, bq1, zacc);
            p0e = n0e; p1e = n1e; p0o = n0o; p1o = n1o;  // renamed (unroll 2)
        }
        macc0 = min3x16(macc0, p0e, p0o);         // drain
        macc1 = min3x16(macc1, p1e, p1o);

        __syncthreads();                     // one barrier/stage (R8/R10 scheme)
    }

    // epilogue (R6-proven mapping): trees, row-halves, +||q||^2, block-sum
    float m0 = mintree(macc0);
    float m1 = mintree(macc1);
    m0 = fminf(m0, __shfl_xor(m0, 32));
    m1 = fminf(m1, __shfl_xor(m1, 32));
    float d = fmaxf((lane < 32 ? m0 : m1) + wq, 0.0f);
    float s = d;
#pragma unroll
    for (int o = 1; o < 64; o <<= 1) s += __shfl_xor(s, o);
    if (lane == 0) psum[wid] = s;
    __syncthreads();
    if (t == 0) {
        float tot = (psum[0] + psum[1]) + (psum[2] + psum[3]);
        atomicAdd(out, tot * (1.0f / (float)TOTAL));
    }
}

extern "C" void kernel_launch(void* const* d_in, const int* in_sizes, int n_in,
                              void* d_out, int out_size, void* d_ws, size_t ws_size,
                              hipStream_t stream) {
    const float* pred = (const float*)d_in[0];   // [B, N, 3]
    const float* gt   = (const float*)d_in[1];   // [B, M, 3]
    float* out = (float*)d_out;

    // ws layout: TgA (2MB), TpA (2MB)
    char* ws = (char*)d_ws;
    uint4* TgA = (uint4*)(ws);
    uint4* TpA = (uint4*)(ws + (size_t)TOTAL * 32);

    hipMemsetAsync(out, 0, sizeof(float), stream);

    chamfer_prep_mfma<<<dim3(TOTAL / BLOCK, 2), BLOCK, 0, stream>>>(
        gt, pred, TgA, TpA);

    chamfer_nn_fused<<<dim3(NPTS / QB, B_SZ, 2), BLOCK, 0, stream>>>(
        TgA, TpA, pred, gt, out);
}